// Round 10
// baseline (246.975 us; speedup 1.0000x reference)
//
#include <hip/hip_runtime.h>

#define TL 2048
#define TC 8
#define TK 84
#define TF 4
#define TD 4
#define AK 96               // padded kernel rows
#define AC 96               // padded reduction dim (kappa = j*8+c, 72 used)
#define ROWS 352            // staged LDS rows of 16B (320 ext + garbage-tap pad)
#define NFEAT (TD * TK * TF)  // 1344
#define A_BYTES (TD * AK * AC * 2)  // 73728

typedef unsigned int u32;
typedef unsigned short u16;
typedef __fp16 hf8 __attribute__((ext_vector_type(8)));
typedef float f32x4 __attribute__((ext_vector_type(4)));

__device__ __forceinline__ u32 pkrtz(float a, float b) {
    return __builtin_bit_cast(u32, __builtin_amdgcn_cvt_pkrtz(a, b));
}
// spread row bits into bank bits; involution within 8-row groups
__device__ __forceinline__ int swzrow(int e) { return e ^ ((e >> 3) & 7); }

__global__ void mr_zero(float* __restrict__ ws) {
    ws[blockIdx.x * 256 + threadIdx.x] = 0.f;   // grid covers 64*NFEAT exactly
}

// A[d][k][kappa] = kern[k][kappa/8] * (cmask[d][k][kappa%8] != 0), fp16, zero-padded
__global__ void mr_prep(const float* __restrict__ kern, const float* __restrict__ cmask,
                        u16* __restrict__ A) {
    const int idx = blockIdx.x * 256 + threadIdx.x;
    if (idx >= TD * AK * AC) return;
    const int d = idx / (AK * AC), r = idx % (AK * AC);
    const int k = r / AC, kap = r % AC;
    float v = 0.f;
    if (k < TK && kap < 72) {
        const float m = cmask[((size_t)d * TK + k) * TC + (kap & 7)];
        v = (m != 0.f) ? kern[k * 9 + (kap >> 3)] : 0.f;
    }
    const __fp16 h = (__fp16)v;
    A[idx] = __builtin_bit_cast(u16, h);
}

__global__ __launch_bounds__(256, 4) void mr_main(
    const float* __restrict__ x,    // [B, L, C]
    const u16*  __restrict__ A,     // [D, AK, AC] fp16
    const float* __restrict__ bias, // [D, TK, TF]
    float* __restrict__ ws)         // [B, NFEAT] raw counts (zeroed)
{
    __shared__ __align__(16) uint4 xh[ROWS];   // 5632 B fp16 signal, [t][c] rows

    const int bx = blockIdx.x;
    const int tc = bx & 7, d = (bx >> 3) & 3, b = bx >> 5;
    const int tid = threadIdx.x, lane = tid & 63, w = tid >> 6;
    const int dil = 1 << d, pad = 4 << d;
    const int t0 = tc * 256;
    const float* xb = x + (size_t)b * TL * TC;

    // ---- stage x (fp16, row-swizzled); rows beyond ext zeroed (garbage taps) ----
    for (int e = tid; e < ROWS; e += 256) {
        const int pos = t0 - 32 + e;
        uint4 v = {0u, 0u, 0u, 0u};
        if (pos >= 0 && pos < TL) {
            const float4* xp = (const float4*)(xb + (size_t)pos * TC);
            const float4 a = xp[0], h = xp[1];
            v.x = pkrtz(a.x, a.y); v.y = pkrtz(a.z, a.w);
            v.z = pkrtz(h.x, h.y); v.w = pkrtz(h.z, h.w);
        }
        xh[swzrow(e)] = v;
    }
    __syncthreads();

    const int col = lane & 15, lg = lane >> 4;
    const int ebase = 32 + col - 4 * dil;       // + tt*16 + (kb*4+lg)*dil
    float* wsb = ws + (size_t)b * NFEAT;

    for (int kt = 0; kt < 6; ++kt) {
        // A fragments: row = kt*16+col (M), kappa = kb*32 + lg*8 + i (K)
        hf8 af[3];
        #pragma unroll
        for (int kb = 0; kb < 3; ++kb)
            af[kb] = __builtin_bit_cast(hf8,
                *(const uint4*)(A + (((size_t)d * AK + kt * 16 + col) * AC) + kb * 32 + lg * 8));

        // biases for this lane's 4 C-rows: k = kt*16 + lg*4 + rg (clamp; k>=84 discarded)
        float4 bq[4];
        #pragma unroll
        for (int rg = 0; rg < 4; ++rg) {
            int k = kt * 16 + lg * 4 + rg;
            k = (k < TK) ? k : (TK - 1);
            bq[rg] = *(const float4*)(bias + ((size_t)d * TK + k) * TF);
        }

        float cnt[4][4];
        #pragma unroll
        for (int rg = 0; rg < 4; ++rg)
            #pragma unroll
            for (int f = 0; f < 4; ++f) cnt[rg][f] = 0.f;

        for (int i = 0; i < 4; ++i) {
            const int tt = w * 4 + i;
            f32x4 C = {0.f, 0.f, 0.f, 0.f};
            #pragma unroll
            for (int kb = 0; kb < 3; ++kb) {
                const int e = ebase + tt * 16 + (kb * 4 + lg) * dil;
                const hf8 bfrag = __builtin_bit_cast(hf8, xh[swzrow(e)]);
                C = __builtin_amdgcn_mfma_f32_16x16x32_f16(af[kb], bfrag, C, 0, 0, 0);
            }
            const int t = t0 + tt * 16 + col;
            const float okf = (t >= pad && t < TL - pad) ? 1.f : 0.f;
            #pragma unroll
            for (int rg = 0; rg < 4; ++rg) {
                const float cv = C[rg];
                const float s = ((d ^ rg) & 1) ? okf : 1.f;  // trim iff (d+k) odd; k parity = rg parity
                cnt[rg][0] += (cv > bq[rg].x) ? s : 0.f;
                cnt[rg][1] += (cv > bq[rg].y) ? s : 0.f;
                cnt[rg][2] += (cv > bq[rg].z) ? s : 0.f;
                cnt[rg][3] += (cv > bq[rg].w) ? s : 0.f;
            }
        }

        // reduce over the 16 t-columns (lane bits 0..3)
        #pragma unroll
        for (int m = 1; m < 16; m <<= 1)
            #pragma unroll
            for (int rg = 0; rg < 4; ++rg)
                #pragma unroll
                for (int f = 0; f < 4; ++f)
                    cnt[rg][f] += __shfl_xor(cnt[rg][f], m, 64);

        if (col == 0) {
            #pragma unroll
            for (int rg = 0; rg < 4; ++rg) {
                const int k = kt * 16 + lg * 4 + rg;
                if (k < TK) {
                    #pragma unroll
                    for (int f = 0; f < 4; ++f)
                        atomicAdd(wsb + (d * TK + k) * TF + f, cnt[rg][f]);
                }
            }
        }
    }
}

__global__ void mr_fin(const float* __restrict__ ws, const float* __restrict__ fmean,
                       const float* __restrict__ fstd, float* __restrict__ out) {
    const int o = blockIdx.x * 256 + threadIdx.x;   // grid covers 64*NFEAT exactly
    const int fid = o % NFEAT;
    const int d = fid / (TK * TF), k = (fid % (TK * TF)) >> 2;
    const float denom = ((d + k) & 1) ? (float)(TL - (8 << d)) : (float)TL;
    out[o] = (ws[o] / denom - fmean[fid]) / fstd[fid];
}

extern "C" void kernel_launch(void* const* d_in, const int* in_sizes, int n_in,
                              void* d_out, int out_size, void* d_ws, size_t ws_size,
                              hipStream_t stream) {
    const float* x     = (const float*)d_in[0];
    const float* kern  = (const float*)d_in[1];
    const float* cmask = (const float*)d_in[2];
    const float* bias  = (const float*)d_in[3];
    const float* fmean = (const float*)d_in[4];
    const float* fstd  = (const float*)d_in[5];
    float* out = (float*)d_out;

    u16*   Aws = (u16*)d_ws;
    float* cws = (float*)((char*)d_ws + A_BYTES);

    hipLaunchKernelGGL(mr_zero, dim3(64 * NFEAT / 256), dim3(256), 0, stream, cws);
    hipLaunchKernelGGL(mr_prep, dim3((TD * AK * AC + 255) / 256), dim3(256), 0, stream,
                       kern, cmask, Aws);
    hipLaunchKernelGGL(mr_main, dim3(64 * TD * 8), dim3(256), 0, stream, x, Aws, bias, cws);
    hipLaunchKernelGGL(mr_fin, dim3(64 * NFEAT / 256), dim3(256), 0, stream,
                       cws, fmean, fstd, out);
}

// Round 12
// 92.156 us; speedup vs baseline: 2.6800x; 2.6800x over previous
//
#include <hip/hip_runtime.h>

#define TL 2048
#define TC 8
#define TK 84
#define TF 4
#define TD 4
#define AK 96               // padded kernel rows
#define AC 96               // padded reduction dim (kappa = j*8+c, 72 used)
#define ROWS 608            // staged LDS rows of 16B: 576 ext + garbage-tap pad
#define NFEAT (TD * TK * TF)  // 1344

typedef unsigned int u32;
typedef unsigned short u16;
typedef __fp16 hf8 __attribute__((ext_vector_type(8)));
typedef float f32x4 __attribute__((ext_vector_type(4)));

__device__ __forceinline__ u32 pkrtz(float a, float b) {
    return __builtin_bit_cast(u32, __builtin_amdgcn_cvt_pkrtz(a, b));
}
// row swizzle: breaks the 8-row bank period of 16B rows; involution per 64-row group
__device__ __forceinline__ int swzrow(int e) { return e ^ ((e >> 3) & 7); }

__global__ void mr_init(const float* __restrict__ fmean, const float* __restrict__ fstd,
                        float* __restrict__ out) {
    const int o = blockIdx.x * 256 + threadIdx.x;   // grid covers 64*NFEAT exactly
    const int fid = o % NFEAT;
    out[o] = -fmean[fid] / fstd[fid];
}

// A[d][k][kappa] = kern[k][kappa/8] * (cmask[d][k][kappa%8] != 0), fp16, zero-padded
__global__ void mr_prep(const float* __restrict__ kern, const float* __restrict__ cmask,
                        u16* __restrict__ A) {
    const int idx = blockIdx.x * 256 + threadIdx.x;
    if (idx >= TD * AK * AC) return;
    const int d = idx / (AK * AC), r = idx % (AK * AC);
    const int k = r / AC, kap = r % AC;
    float v = 0.f;
    if (k < TK && kap < 72) {
        const float m = cmask[((size_t)d * TK + k) * TC + (kap & 7)];
        v = (m != 0.f) ? kern[k * 9 + (kap >> 3)] : 0.f;
    }
    const __fp16 h = (__fp16)v;
    A[idx] = __builtin_bit_cast(u16, h);
}

__global__ __launch_bounds__(256, 4) void mr_main(
    const float* __restrict__ x,    // [B, L, C]
    const u16*  __restrict__ A,     // [D, AK, AC] fp16
    const float* __restrict__ bias, // [D, TK, TF]
    const float* __restrict__ fstd, // [NFEAT]
    float* __restrict__ out)        // [B, NFEAT], pre-init to -mean/std
{
    __shared__ __align__(16) uint4 xh[ROWS];   // 9728 B fp16 signal, [t][c] rows
    __shared__ int feats[TK][TF];              // 1344 B

    const int bx = blockIdx.x;
    const int q = bx & 3, d = (bx >> 2) & 3, b = bx >> 4;
    const int tid = threadIdx.x, lane = tid & 63, w = tid >> 6;
    const int dil = 1 << d, pad = 4 << d;
    const int t0 = q * 512;
    const float* xb = x + (size_t)b * TL * TC;

    for (int i2 = tid; i2 < TK * TF; i2 += 256) ((int*)feats)[i2] = 0;

    // ---- stage x (fp16, row-swizzled); OOB rows zeroed ----
    for (int e = tid; e < ROWS; e += 256) {
        const int pos = t0 - 32 + e;
        uint4 v = {0u, 0u, 0u, 0u};
        if (pos >= 0 && pos < TL) {
            const float4* xp = (const float4*)(xb + (size_t)pos * TC);
            const float4 a = xp[0], h = xp[1];
            v.x = pkrtz(a.x, a.y); v.y = pkrtz(a.z, a.w);
            v.z = pkrtz(h.x, h.y); v.w = pkrtz(h.z, h.w);
        }
        xh[swzrow(e)] = v;
    }
    __syncthreads();

    const int col = lane & 15, lg = lane >> 4;
    const int ebase = 32 + col - 4 * dil;       // + tt*16 + (kb*4+lg)*dil

    for (int kt = 0; kt < 6; ++kt) {
        // A fragments: row = kt*16+col (M), kappa = kb*32 + lg*8 + i (K)
        hf8 af[3];
        #pragma unroll
        for (int kb = 0; kb < 3; ++kb)
            af[kb] = __builtin_bit_cast(hf8,
                *(const uint4*)(A + (((size_t)d * AK + kt * 16 + col) * AC) + kb * 32 + lg * 8));

        // biases for this lane's 4 C-rows: k = kt*16 + lg*4 + rg (clamped; k>=84 discarded)
        float4 bq[4];
        #pragma unroll
        for (int rg = 0; rg < 4; ++rg) {
            int k = kt * 16 + lg * 4 + rg;
            k = (k < TK) ? k : (TK - 1);
            bq[rg] = *(const float4*)(bias + ((size_t)d * TK + k) * TF);
        }

        int cnt[4][4];
        #pragma unroll
        for (int rg = 0; rg < 4; ++rg)
            #pragma unroll
            for (int f = 0; f < 4; ++f) cnt[rg][f] = 0;

        #pragma unroll
        for (int i = 0; i < 8; ++i) {
            const int tt = w * 8 + i;           // this wave's t-tile (of 32)
            f32x4 C = {0.f, 0.f, 0.f, 0.f};
            #pragma unroll
            for (int kb = 0; kb < 3; ++kb) {
                const int e = ebase + tt * 16 + (kb * 4 + lg) * dil;
                const hf8 bfrag = __builtin_bit_cast(hf8, xh[swzrow(e)]);
                C = __builtin_amdgcn_mfma_f32_16x16x32_f16(af[kb], bfrag, C, 0, 0, 0);
            }
            const int t = t0 + tt * 16 + col;
            const bool ok = (t >= pad && t < TL - pad);
            #pragma unroll
            for (int rg = 0; rg < 4; ++rg) {
                const float cv = C[rg];
                const bool use = ((d ^ rg) & 1) ? ok : true;  // trim iff (d+k) odd; k parity = rg parity
                cnt[rg][0] += (use && cv > bq[rg].x) ? 1 : 0;
                cnt[rg][1] += (use && cv > bq[rg].y) ? 1 : 0;
                cnt[rg][2] += (use && cv > bq[rg].z) ? 1 : 0;
                cnt[rg][3] += (use && cv > bq[rg].w) ? 1 : 0;
            }
        }

        // reduce over the 16 t-columns (lane bits 0..3), then LDS atomics (4-way)
        #pragma unroll
        for (int m = 1; m < 16; m <<= 1)
            #pragma unroll
            for (int rg = 0; rg < 4; ++rg)
                #pragma unroll
                for (int f = 0; f < 4; ++f)
                    cnt[rg][f] += __shfl_xor(cnt[rg][f], m, 64);

        if (col == 0) {
            #pragma unroll
            for (int rg = 0; rg < 4; ++rg) {
                const int k = kt * 16 + lg * 4 + rg;
                if (k < TK) {
                    #pragma unroll
                    for (int f = 0; f < 4; ++f)
                        atomicAdd(&feats[k][f], cnt[rg][f]);
                }
            }
        }
    }

    // ---- epilogue: parallel global atomics, strided over ALL 336 features ----
    __syncthreads();
    for (int idx = tid; idx < TK * TF; idx += 256) {
        const int k = idx >> 2;
        const bool odd2 = ((d + k) & 1) != 0;
        const float denom = odd2 ? (float)(TL - (8 << d)) : (float)TL;
        const int fid = d * (TK * TF) + idx;
        const float scale = 1.0f / (denom * fstd[fid]);
        atomicAdd(&out[(size_t)b * NFEAT + fid], (float)feats[k][idx & 3] * scale);
    }
}

extern "C" void kernel_launch(void* const* d_in, const int* in_sizes, int n_in,
                              void* d_out, int out_size, void* d_ws, size_t ws_size,
                              hipStream_t stream) {
    const float* x     = (const float*)d_in[0];
    const float* kern  = (const float*)d_in[1];
    const float* cmask = (const float*)d_in[2];
    const float* bias  = (const float*)d_in[3];
    const float* fmean = (const float*)d_in[4];
    const float* fstd  = (const float*)d_in[5];
    float* out = (float*)d_out;
    u16* Aws = (u16*)d_ws;   // 73728 B

    hipLaunchKernelGGL(mr_init, dim3(64 * NFEAT / 256), dim3(256), 0, stream,
                       fmean, fstd, out);
    hipLaunchKernelGGL(mr_prep, dim3((TD * AK * AC + 255) / 256), dim3(256), 0, stream,
                       kern, cmask, Aws);
    hipLaunchKernelGGL(mr_main, dim3(64 * TD * 4), dim3(256), 0, stream,
                       x, Aws, bias, fstd, out);
}

// Round 13
// 86.811 us; speedup vs baseline: 2.8450x; 1.0616x over previous
//
#include <hip/hip_runtime.h>

#define TL 2048
#define TC 8
#define TK 84
#define TF 4
#define TD 4
#define ROWS 608            // staged LDS rows of 16B: 576 ext + garbage-tap pad
#define NFEAT (TD * TK * TF)  // 1344

typedef unsigned int u32;
typedef unsigned short u16;
typedef __fp16 hf8 __attribute__((ext_vector_type(8)));
typedef float f32x4 __attribute__((ext_vector_type(4)));

__device__ __forceinline__ u32 pkrtz(float a, float b) {
    return __builtin_bit_cast(u32, __builtin_amdgcn_cvt_pkrtz(a, b));
}
// row swizzle: breaks the 8-row bank period of 16B rows; involution per 64-row group
__device__ __forceinline__ int swzrow(int e) { return e ^ ((e >> 3) & 7); }

__global__ void mr_init(const float* __restrict__ fmean, const float* __restrict__ fstd,
                        float* __restrict__ out) {
    const int o = blockIdx.x * 256 + threadIdx.x;   // grid covers 64*NFEAT exactly
    const int fid = o % NFEAT;
    out[o] = -fmean[fid] / fstd[fid];
}

__global__ __launch_bounds__(256, 4) void mr_main(
    const float* __restrict__ x,     // [B, L, C]
    const float* __restrict__ kern,  // [K, 9]
    const float* __restrict__ cmask, // [D, K, C]
    const float* __restrict__ bias,  // [D, TK, TF]
    const float* __restrict__ fstd,  // [NFEAT]
    float* __restrict__ out)         // [B, NFEAT], pre-init to -mean/std
{
    __shared__ __align__(16) uint4 xh[ROWS];     // 9728 B fp16 signal, [t][c] rows
    __shared__ __align__(16) uint4 Alds[1152];   // 18432 B masked-weight fragments
    __shared__ __align__(16) float4 blds[TK];    // 1344 B biases
    __shared__ int feats[TK][TF];                // 1344 B

    const int bx = blockIdx.x;
    const int q = bx & 3, d = (bx >> 2) & 3, b = bx >> 4;
    const int tid = threadIdx.x, lane = tid & 63, w = tid >> 6;
    const int dil = 1 << d, pad = 4 << d;
    const int t0 = q * 512;
    const float* xb = x + (size_t)b * TL * TC;

    for (int i2 = tid; i2 < TK * TF; i2 += 256) ((int*)feats)[i2] = 0;
    if (tid < TK) blds[tid] = *(const float4*)(bias + ((size_t)d * TK + tid) * TF);

    // ---- build A fragments in LDS: Alds[(kt*3+kb)*64 + lg*16 + col] ----
    // one fragment = kern[k][kb*4+lg] masked by cmask[d][k][0..7], fp16 x8
    for (int f = tid; f < 1152; f += 256) {
        const int col = f & 15, lg = (f >> 4) & 3, kbkt = f >> 6;
        const int kt = kbkt / 3, kb = kbkt % 3;
        const int k = kt * 16 + col, j = kb * 4 + lg;
        uint4 v = {0u, 0u, 0u, 0u};
        if (k < TK && j < 9) {
            const float wv = kern[k * 9 + j];
            const float* mp = cmask + ((size_t)d * TK + k) * TC;
            const float4 m0 = *(const float4*)mp;
            const float4 m1 = *(const float4*)(mp + 4);
            v.x = pkrtz(m0.x != 0.f ? wv : 0.f, m0.y != 0.f ? wv : 0.f);
            v.y = pkrtz(m0.z != 0.f ? wv : 0.f, m0.w != 0.f ? wv : 0.f);
            v.z = pkrtz(m1.x != 0.f ? wv : 0.f, m1.y != 0.f ? wv : 0.f);
            v.w = pkrtz(m1.z != 0.f ? wv : 0.f, m1.w != 0.f ? wv : 0.f);
        }
        Alds[f] = v;
    }

    // ---- stage x (fp16, row-swizzled); OOB rows zeroed ----
    for (int e = tid; e < ROWS; e += 256) {
        const int pos = t0 - 32 + e;
        uint4 v = {0u, 0u, 0u, 0u};
        if (pos >= 0 && pos < TL) {
            const float4* xp = (const float4*)(xb + (size_t)pos * TC);
            const float4 a = xp[0], h = xp[1];
            v.x = pkrtz(a.x, a.y); v.y = pkrtz(a.z, a.w);
            v.z = pkrtz(h.x, h.y); v.w = pkrtz(h.z, h.w);
        }
        xh[swzrow(e)] = v;
    }
    __syncthreads();

    const int col = lane & 15, lg = lane >> 4;
    const int ebase = 32 + col - 4 * dil;       // + tt*16 + (kb*4+lg)*dil

    for (int kt = 0; kt < 6; ++kt) {
        hf8 af[3];
        #pragma unroll
        for (int kb = 0; kb < 3; ++kb)
            af[kb] = __builtin_bit_cast(hf8, Alds[(kt * 3 + kb) * 64 + lg * 16 + col]);

        // biases for this lane's 4 C-rows: k = kt*16 + lg*4 + rg (clamped; k>=84 discarded)
        float4 bq[4];
        #pragma unroll
        for (int rg = 0; rg < 4; ++rg) {
            int k = kt * 16 + lg * 4 + rg;
            k = (k < TK) ? k : (TK - 1);
            bq[rg] = blds[k];
        }

        int cnt[4][4];
        #pragma unroll
        for (int rg = 0; rg < 4; ++rg)
            #pragma unroll
            for (int f = 0; f < 4; ++f) cnt[rg][f] = 0;

        #pragma unroll
        for (int i = 0; i < 8; ++i) {
            const int tt = w * 8 + i;           // this wave's t-tile (of 32)
            f32x4 C = {0.f, 0.f, 0.f, 0.f};
            #pragma unroll
            for (int kb = 0; kb < 3; ++kb) {
                const int e = ebase + tt * 16 + (kb * 4 + lg) * dil;
                const hf8 bfrag = __builtin_bit_cast(hf8, xh[swzrow(e)]);
                C = __builtin_amdgcn_mfma_f32_16x16x32_f16(af[kb], bfrag, C, 0, 0, 0);
            }
            const int t = t0 + tt * 16 + col;
            const bool ok = (t >= pad && t < TL - pad);
            #pragma unroll
            for (int rg = 0; rg < 4; ++rg) {
                const float cv = C[rg];
                const bool use = ((d ^ rg) & 1) ? ok : true;  // trim iff (d+k) odd; k parity = rg parity
                cnt[rg][0] += (use && cv > bq[rg].x) ? 1 : 0;
                cnt[rg][1] += (use && cv > bq[rg].y) ? 1 : 0;
                cnt[rg][2] += (use && cv > bq[rg].z) ? 1 : 0;
                cnt[rg][3] += (use && cv > bq[rg].w) ? 1 : 0;
            }
        }

        // reduce over the 16 t-columns (lane bits 0..3), then LDS atomics (4-way)
        #pragma unroll
        for (int m = 1; m < 16; m <<= 1)
            #pragma unroll
            for (int rg = 0; rg < 4; ++rg)
                #pragma unroll
                for (int f = 0; f < 4; ++f)
                    cnt[rg][f] += __shfl_xor(cnt[rg][f], m, 64);

        if (col == 0) {
            #pragma unroll
            for (int rg = 0; rg < 4; ++rg) {
                const int k = kt * 16 + lg * 4 + rg;
                if (k < TK) {
                    #pragma unroll
                    for (int f = 0; f < 4; ++f)
                        atomicAdd(&feats[k][f], cnt[rg][f]);
                }
            }
        }
    }

    // ---- epilogue: parallel global atomics, strided over ALL 336 features ----
    __syncthreads();
    for (int idx = tid; idx < TK * TF; idx += 256) {
        const int k = idx >> 2;
        const bool odd2 = ((d + k) & 1) != 0;
        const float denom = odd2 ? (float)(TL - (8 << d)) : (float)TL;
        const int fid = d * (TK * TF) + idx;
        const float scale = 1.0f / (denom * fstd[fid]);
        atomicAdd(&out[(size_t)b * NFEAT + fid], (float)feats[k][idx & 3] * scale);
    }
}

extern "C" void kernel_launch(void* const* d_in, const int* in_sizes, int n_in,
                              void* d_out, int out_size, void* d_ws, size_t ws_size,
                              hipStream_t stream) {
    const float* x     = (const float*)d_in[0];
    const float* kern  = (const float*)d_in[1];
    const float* cmask = (const float*)d_in[2];
    const float* bias  = (const float*)d_in[3];
    const float* fmean = (const float*)d_in[4];
    const float* fstd  = (const float*)d_in[5];
    float* out = (float*)d_out;

    hipLaunchKernelGGL(mr_init, dim3(64 * NFEAT / 256), dim3(256), 0, stream,
                       fmean, fstd, out);
    hipLaunchKernelGGL(mr_main, dim3(64 * TD * 4), dim3(256), 0, stream,
                       x, kern, cmask, bias, fstd, out);
}

// Round 14
// 84.297 us; speedup vs baseline: 2.9298x; 1.0298x over previous
//
#include <hip/hip_runtime.h>

#define TL 2048
#define TC 8
#define TK 84
#define TF 4
#define TD 4
#define ROWS 608            // staged LDS rows of 16B: 576 ext + garbage-tap pad
#define NFEAT (TD * TK * TF)  // 1344
#define KF (TK * TF)          // 336

typedef unsigned int u32;
typedef unsigned short u16;
typedef __fp16 hf8 __attribute__((ext_vector_type(8)));
typedef float f32x4 __attribute__((ext_vector_type(4)));

__device__ __forceinline__ u32 pkrtz(float a, float b) {
    return __builtin_bit_cast(u32, __builtin_amdgcn_cvt_pkrtz(a, b));
}
// row swizzle: breaks the 8-row bank period of 16B rows; involution per 64-row group
__device__ __forceinline__ int swzrow(int e) { return e ^ ((e >> 3) & 7); }

__global__ __launch_bounds__(256, 4) void mr_main(
    const float* __restrict__ x,     // [B, L, C]
    const float* __restrict__ kern,  // [K, 9]
    const float* __restrict__ cmask, // [D, K, C]
    const float* __restrict__ bias,  // [D, TK, TF]
    int* __restrict__ ws)            // [1024][KF] per-block partial counts
{
    __shared__ __align__(16) uint4 xh[ROWS];     // 9728 B fp16 signal, [t][c] rows
    __shared__ __align__(16) uint4 Alds[1152];   // 18432 B masked-weight fragments
    __shared__ __align__(16) float4 blds[TK];    // 1344 B biases
    __shared__ int feats[TK][TF];                // 1344 B

    const int bx = blockIdx.x;
    const int q = bx & 3, d = (bx >> 2) & 3, b = bx >> 4;
    const int tid = threadIdx.x, lane = tid & 63, w = tid >> 6;
    const int dil = 1 << d, pad = 4 << d;
    const int t0 = q * 512;
    const float* xb = x + (size_t)b * TL * TC;

    for (int i2 = tid; i2 < TK * TF; i2 += 256) ((int*)feats)[i2] = 0;
    if (tid < TK) blds[tid] = *(const float4*)(bias + ((size_t)d * TK + tid) * TF);

    // ---- build A fragments in LDS: Alds[(kt*3+kb)*64 + lg*16 + col] ----
    for (int f = tid; f < 1152; f += 256) {
        const int col = f & 15, lg = (f >> 4) & 3, kbkt = f >> 6;
        const int kt = kbkt / 3, kb = kbkt % 3;
        const int k = kt * 16 + col, j = kb * 4 + lg;
        uint4 v = {0u, 0u, 0u, 0u};
        if (k < TK && j < 9) {
            const float wv = kern[k * 9 + j];
            const float* mp = cmask + ((size_t)d * TK + k) * TC;
            const float4 m0 = *(const float4*)mp;
            const float4 m1 = *(const float4*)(mp + 4);
            v.x = pkrtz(m0.x != 0.f ? wv : 0.f, m0.y != 0.f ? wv : 0.f);
            v.y = pkrtz(m0.z != 0.f ? wv : 0.f, m0.w != 0.f ? wv : 0.f);
            v.z = pkrtz(m1.x != 0.f ? wv : 0.f, m1.y != 0.f ? wv : 0.f);
            v.w = pkrtz(m1.z != 0.f ? wv : 0.f, m1.w != 0.f ? wv : 0.f);
        }
        Alds[f] = v;
    }

    // ---- stage x (fp16, row-swizzled); OOB rows zeroed ----
    for (int e = tid; e < ROWS; e += 256) {
        const int pos = t0 - 32 + e;
        uint4 v = {0u, 0u, 0u, 0u};
        if (pos >= 0 && pos < TL) {
            const float4* xp = (const float4*)(xb + (size_t)pos * TC);
            const float4 a = xp[0], h = xp[1];
            v.x = pkrtz(a.x, a.y); v.y = pkrtz(a.z, a.w);
            v.z = pkrtz(h.x, h.y); v.w = pkrtz(h.z, h.w);
        }
        xh[swzrow(e)] = v;
    }
    __syncthreads();

    const int col = lane & 15, lg = lane >> 4;
    const int ebase = 32 + col - 4 * dil;       // + tt*16 + (kb*4+lg)*dil

    for (int kt = 0; kt < 6; ++kt) {
        hf8 af[3];
        #pragma unroll
        for (int kb = 0; kb < 3; ++kb)
            af[kb] = __builtin_bit_cast(hf8, Alds[(kt * 3 + kb) * 64 + lg * 16 + col]);

        float4 bq[4];
        #pragma unroll
        for (int rg = 0; rg < 4; ++rg) {
            int k = kt * 16 + lg * 4 + rg;
            k = (k < TK) ? k : (TK - 1);
            bq[rg] = blds[k];
        }

        int cnt[4][4];
        #pragma unroll
        for (int rg = 0; rg < 4; ++rg)
            #pragma unroll
            for (int f = 0; f < 4; ++f) cnt[rg][f] = 0;

        #pragma unroll
        for (int i = 0; i < 8; ++i) {
            const int tt = w * 8 + i;           // this wave's t-tile (of 32)
            f32x4 C = {0.f, 0.f, 0.f, 0.f};
            #pragma unroll
            for (int kb = 0; kb < 3; ++kb) {
                const int e = ebase + tt * 16 + (kb * 4 + lg) * dil;
                const hf8 bfrag = __builtin_bit_cast(hf8, xh[swzrow(e)]);
                C = __builtin_amdgcn_mfma_f32_16x16x32_f16(af[kb], bfrag, C, 0, 0, 0);
            }
            const int t = t0 + tt * 16 + col;
            const bool ok = (t >= pad && t < TL - pad);
            #pragma unroll
            for (int rg = 0; rg < 4; ++rg) {
                const float cv = C[rg];
                const bool use = ((d ^ rg) & 1) ? ok : true;  // trim iff (d+k) odd
                cnt[rg][0] += (use && cv > bq[rg].x) ? 1 : 0;
                cnt[rg][1] += (use && cv > bq[rg].y) ? 1 : 0;
                cnt[rg][2] += (use && cv > bq[rg].z) ? 1 : 0;
                cnt[rg][3] += (use && cv > bq[rg].w) ? 1 : 0;
            }
        }

        // reduce over the 16 t-columns (lane bits 0..3), then LDS atomics
        #pragma unroll
        for (int m = 1; m < 16; m <<= 1)
            #pragma unroll
            for (int rg = 0; rg < 4; ++rg)
                #pragma unroll
                for (int f = 0; f < 4; ++f)
                    cnt[rg][f] += __shfl_xor(cnt[rg][f], m, 64);

        if (col == 0) {
            #pragma unroll
            for (int rg = 0; rg < 4; ++rg) {
                const int k = kt * 16 + lg * 4 + rg;
                if (k < TK) {
                    #pragma unroll
                    for (int f = 0; f < 4; ++f)
                        atomicAdd(&feats[k][f], cnt[rg][f]);
                }
            }
        }
    }

    // ---- epilogue: plain coalesced partial stores (no global atomics) ----
    __syncthreads();
    for (int idx = tid; idx < KF; idx += 256)
        ws[(size_t)bx * KF + idx] = feats[idx >> 2][idx & 3];
}

// Reduce 4 q-partials, normalize, write out. Grid covers 64*NFEAT exactly.
__global__ void mr_fin(const int* __restrict__ ws, const float* __restrict__ fmean,
                       const float* __restrict__ fstd, float* __restrict__ out) {
    const int o = blockIdx.x * 256 + threadIdx.x;
    const int fid = o % NFEAT, b = o / NFEAT;
    const int d = fid / KF, idx = fid % KF, k = idx >> 2;
    const int base = ((b * 16 + d * 4) * KF) + idx;
    const int cnt = ws[base] + ws[base + KF] + ws[base + 2 * KF] + ws[base + 3 * KF];
    const float denom = ((d + k) & 1) ? (float)(TL - (8 << d)) : (float)TL;
    out[o] = ((float)cnt / denom - fmean[fid]) / fstd[fid];
}

extern "C" void kernel_launch(void* const* d_in, const int* in_sizes, int n_in,
                              void* d_out, int out_size, void* d_ws, size_t ws_size,
                              hipStream_t stream) {
    const float* x     = (const float*)d_in[0];
    const float* kern  = (const float*)d_in[1];
    const float* cmask = (const float*)d_in[2];
    const float* bias  = (const float*)d_in[3];
    const float* fmean = (const float*)d_in[4];
    const float* fstd  = (const float*)d_in[5];
    float* out = (float*)d_out;
    int* ws = (int*)d_ws;   // 1024*336*4 = 1376256 B

    hipLaunchKernelGGL(mr_main, dim3(64 * TD * 4), dim3(256), 0, stream,
                       x, kern, cmask, bias, ws);
    hipLaunchKernelGGL(mr_fin, dim3(64 * NFEAT / 256), dim3(256), 0, stream,
                       ws, fmean, fstd, out);
}

// Round 15
// 40.241 us; speedup vs baseline: 6.1375x; 2.0948x over previous
//
#include <hip/hip_runtime.h>

#define TL 2048
#define TC 8
#define TK 84
#define TF 4
#define TD 4
#define ROWS 608            // staged LDS rows of 16B: 576 ext + garbage-tap pad
#define NFEAT (TD * TK * TF)  // 1344
#define KF (TK * TF)          // 336

typedef unsigned int u32;
typedef unsigned short u16;
typedef __fp16 hf8 __attribute__((ext_vector_type(8)));
typedef float f32x4 __attribute__((ext_vector_type(4)));

__device__ __forceinline__ u32 pkrtz(float a, float b) {
    return __builtin_bit_cast(u32, __builtin_amdgcn_cvt_pkrtz(a, b));
}
// row swizzle: breaks the 8-row bank period of 16B rows; involution per 64-row group
__device__ __forceinline__ int swzrow(int e) { return e ^ ((e >> 3) & 7); }

__global__ __launch_bounds__(256, 4) void mr_main(
    const float* __restrict__ x,     // [B, L, C]
    const float* __restrict__ kern,  // [K, 9]
    const float* __restrict__ cmask, // [D, K, C]
    const float* __restrict__ bias,  // [D, TK, TF]
    int* __restrict__ ws)            // [1024][KF] per-block partial counts
{
    __shared__ __align__(16) uint4 xh[ROWS];     // 9728 B fp16 signal, [t][c] rows
    __shared__ __align__(16) uint4 Alds[1152];   // 18432 B masked-weight fragments
    __shared__ __align__(16) float4 blds[TK];    // 1344 B biases
    __shared__ int feats[TK][TF];                // 1344 B

    const int bx = blockIdx.x;
    const int q = bx & 3, d = (bx >> 2) & 3, b = bx >> 4;
    const int tid = threadIdx.x, lane = tid & 63, w = tid >> 6;
    const int dil = 1 << d, pad = 4 << d;
    const int t0 = q * 512;
    const float* xb = x + (size_t)b * TL * TC;

    for (int i2 = tid; i2 < TK * TF; i2 += 256) ((int*)feats)[i2] = 0;
    if (tid < TK) blds[tid] = *(const float4*)(bias + ((size_t)d * TK + tid) * TF);

    // ---- build A fragments in LDS: Alds[(kt*3+kb)*64 + lg*16 + col] ----
    for (int f = tid; f < 1152; f += 256) {
        const int col = f & 15, lg = (f >> 4) & 3, kbkt = f >> 6;
        const int kt = kbkt / 3, kb = kbkt % 3;
        const int k = kt * 16 + col, j = kb * 4 + lg;
        uint4 v = {0u, 0u, 0u, 0u};
        if (k < TK && j < 9) {
            const float wv = kern[k * 9 + j];
            const float* mp = cmask + ((size_t)d * TK + k) * TC;
            const float4 m0 = *(const float4*)mp;
            const float4 m1 = *(const float4*)(mp + 4);
            v.x = pkrtz(m0.x != 0.f ? wv : 0.f, m0.y != 0.f ? wv : 0.f);
            v.y = pkrtz(m0.z != 0.f ? wv : 0.f, m0.w != 0.f ? wv : 0.f);
            v.z = pkrtz(m1.x != 0.f ? wv : 0.f, m1.y != 0.f ? wv : 0.f);
            v.w = pkrtz(m1.z != 0.f ? wv : 0.f, m1.w != 0.f ? wv : 0.f);
        }
        Alds[f] = v;
    }

    // ---- stage x (fp16, row-swizzled); OOB rows zeroed ----
    for (int e = tid; e < ROWS; e += 256) {
        const int pos = t0 - 32 + e;
        uint4 v = {0u, 0u, 0u, 0u};
        if (pos >= 0 && pos < TL) {
            const float4* xp = (const float4*)(xb + (size_t)pos * TC);
            const float4 a = xp[0], h = xp[1];
            v.x = pkrtz(a.x, a.y); v.y = pkrtz(a.z, a.w);
            v.z = pkrtz(h.x, h.y); v.w = pkrtz(h.z, h.w);
        }
        xh[swzrow(e)] = v;
    }
    __syncthreads();

    const int col = lane & 15, lg = lane >> 4;
    const int ebase = 32 + col - 4 * dil;       // + tt*16 + (kb*4+lg)*dil

    for (int kt = 0; kt < 6; ++kt) {
        hf8 af[3];
        #pragma unroll
        for (int kb = 0; kb < 3; ++kb)
            af[kb] = __builtin_bit_cast(hf8, Alds[(kt * 3 + kb) * 64 + lg * 16 + col]);

        float4 bq[4];
        #pragma unroll
        for (int rg = 0; rg < 4; ++rg) {
            int k = kt * 16 + lg * 4 + rg;
            k = (k < TK) ? k : (TK - 1);
            bq[rg] = blds[k];
        }

        // packed byte counters: field f at bits [8f,8f+8); per-lane max 8, reduced max 128
        u32 cnt[4] = {0u, 0u, 0u, 0u};

        #pragma unroll 2
        for (int i = 0; i < 8; ++i) {
            const int tt = w * 8 + i;           // this wave's t-tile (of 32)
            f32x4 C = {0.f, 0.f, 0.f, 0.f};
            #pragma unroll
            for (int kb = 0; kb < 3; ++kb) {
                const int e = ebase + tt * 16 + (kb * 4 + lg) * dil;
                const hf8 bfrag = __builtin_bit_cast(hf8, xh[swzrow(e)]);
                C = __builtin_amdgcn_mfma_f32_16x16x32_f16(af[kb], bfrag, C, 0, 0, 0);
            }
            const int t = t0 + tt * 16 + col;
            const bool ok = (t >= pad && t < TL - pad);
            #pragma unroll
            for (int rg = 0; rg < 4; ++rg) {
                const float cv = C[rg];
                const bool use = ((d ^ rg) & 1) ? ok : true;  // trim iff (d+k) odd
                cnt[rg] += (use && cv > bq[rg].x) ? 0x1u : 0u;
                cnt[rg] += (use && cv > bq[rg].y) ? 0x100u : 0u;
                cnt[rg] += (use && cv > bq[rg].z) ? 0x10000u : 0u;
                cnt[rg] += (use && cv > bq[rg].w) ? 0x1000000u : 0u;
            }
        }

        // reduce over the 16 t-columns (lane bits 0..3); packed adds can't carry
        #pragma unroll
        for (int m = 1; m < 16; m <<= 1)
            #pragma unroll
            for (int rg = 0; rg < 4; ++rg)
                cnt[rg] += __shfl_xor(cnt[rg], m, 64);

        if (col == 0) {
            #pragma unroll
            for (int rg = 0; rg < 4; ++rg) {
                const int k = kt * 16 + lg * 4 + rg;
                if (k < TK) {
                    #pragma unroll
                    for (int f = 0; f < 4; ++f)
                        atomicAdd(&feats[k][f], (int)((cnt[rg] >> (8 * f)) & 0xFFu));
                }
            }
        }
    }

    // ---- epilogue: plain coalesced partial stores (no global atomics) ----
    __syncthreads();
    for (int idx = tid; idx < KF; idx += 256)
        ws[(size_t)bx * KF + idx] = feats[idx >> 2][idx & 3];
}

// Reduce 4 q-partials, normalize, write out. Grid covers 64*NFEAT exactly.
__global__ void mr_fin(const int* __restrict__ ws, const float* __restrict__ fmean,
                       const float* __restrict__ fstd, float* __restrict__ out) {
    const int o = blockIdx.x * 256 + threadIdx.x;
    const int fid = o % NFEAT, b = o / NFEAT;
    const int d = fid / KF, idx = fid % KF, k = idx >> 2;
    const int base = ((b * 16 + d * 4) * KF) + idx;
    const int cnt = ws[base] + ws[base + KF] + ws[base + 2 * KF] + ws[base + 3 * KF];
    const float denom = ((d + k) & 1) ? (float)(TL - (8 << d)) : (float)TL;
    out[o] = ((float)cnt / denom - fmean[fid]) / fstd[fid];
}

extern "C" void kernel_launch(void* const* d_in, const int* in_sizes, int n_in,
                              void* d_out, int out_size, void* d_ws, size_t ws_size,
                              hipStream_t stream) {
    const float* x     = (const float*)d_in[0];
    const float* kern  = (const float*)d_in[1];
    const float* cmask = (const float*)d_in[2];
    const float* bias  = (const float*)d_in[3];
    const float* fmean = (const float*)d_in[4];
    const float* fstd  = (const float*)d_in[5];
    float* out = (float*)d_out;
    int* ws = (int*)d_ws;   // 1024*336*4 = 1376256 B

    hipLaunchKernelGGL(mr_main, dim3(64 * TD * 4), dim3(256), 0, stream,
                       x, kern, cmask, bias, ws);
    hipLaunchKernelGGL(mr_fin, dim3(64 * NFEAT / 256), dim3(256), 0, stream,
                       ws, fmean, fstd, out);
}

// Round 16
// 38.623 us; speedup vs baseline: 6.3946x; 1.0419x over previous
//
#include <hip/hip_runtime.h>

#define TL 2048
#define TC 8
#define TK 84
#define TF 4
#define TD 4
#define ROWS 352            // staged LDS rows of 16B: 320 ext + swizzle pad
#define NFEAT (TD * TK * TF)  // 1344
#define KF (TK * TF)          // 336
#define NQ 8                  // t-chunks per (b,d)

typedef unsigned int u32;
typedef __fp16 hf8 __attribute__((ext_vector_type(8)));
typedef float f32x4 __attribute__((ext_vector_type(4)));

__device__ __forceinline__ u32 pkrtz(float a, float b) {
    return __builtin_bit_cast(u32, __builtin_amdgcn_cvt_pkrtz(a, b));
}
// row swizzle: breaks the 8-row bank period of 16B rows; involution per 8-row group
__device__ __forceinline__ int swzrow(int e) { return e ^ ((e >> 3) & 7); }

__global__ __launch_bounds__(256, 4) void mr_main(
    const float* __restrict__ x,     // [B, L, C]
    const float* __restrict__ kern,  // [K, 9]
    const float* __restrict__ cmask, // [D, K, C]
    const float* __restrict__ bias,  // [D, TK, TF]
    int* __restrict__ ws)            // [2048][KF] per-block partial counts
{
    __shared__ __align__(16) uint4 xh[ROWS];     // 5632 B fp16 signal, [t][c] rows
    __shared__ __align__(16) uint4 Alds[1152];   // 18432 B masked-weight fragments
    __shared__ __align__(16) float4 blds[TK];    // 1344 B biases
    __shared__ int feats[TK][TF];                // 1344 B

    const int bx = blockIdx.x;
    const int q = bx & 7, d = (bx >> 3) & 3, b = bx >> 5;
    const int tid = threadIdx.x, lane = tid & 63, w = tid >> 6;
    const int dil = 1 << d, pad = 4 << d;
    const int t0 = q * 256;
    const float* xb = x + (size_t)b * TL * TC;

    for (int i2 = tid; i2 < TK * TF; i2 += 256) ((int*)feats)[i2] = 0;
    if (tid < TK) blds[tid] = *(const float4*)(bias + ((size_t)d * TK + tid) * TF);

    // ---- build A fragments in LDS: Alds[(kt*3+kb)*64 + lg*16 + col] ----
    for (int f = tid; f < 1152; f += 256) {
        const int col = f & 15, lg = (f >> 4) & 3, kbkt = f >> 6;
        const int kt = kbkt / 3, kb = kbkt % 3;
        const int k = kt * 16 + col, j = kb * 4 + lg;
        uint4 v = {0u, 0u, 0u, 0u};
        if (k < TK && j < 9) {
            const float wv = kern[k * 9 + j];
            const float* mp = cmask + ((size_t)d * TK + k) * TC;
            const float4 m0 = *(const float4*)mp;
            const float4 m1 = *(const float4*)(mp + 4);
            v.x = pkrtz(m0.x != 0.f ? wv : 0.f, m0.y != 0.f ? wv : 0.f);
            v.y = pkrtz(m0.z != 0.f ? wv : 0.f, m0.w != 0.f ? wv : 0.f);
            v.z = pkrtz(m1.x != 0.f ? wv : 0.f, m1.y != 0.f ? wv : 0.f);
            v.w = pkrtz(m1.z != 0.f ? wv : 0.f, m1.w != 0.f ? wv : 0.f);
        }
        Alds[f] = v;
    }

    // ---- stage x (fp16, row-swizzled); OOB rows zeroed ----
    for (int e = tid; e < ROWS; e += 256) {
        const int pos = t0 - 32 + e;
        uint4 v = {0u, 0u, 0u, 0u};
        if (pos >= 0 && pos < TL) {
            const float4* xp = (const float4*)(xb + (size_t)pos * TC);
            const float4 a = xp[0], h = xp[1];
            v.x = pkrtz(a.x, a.y); v.y = pkrtz(a.z, a.w);
            v.z = pkrtz(h.x, h.y); v.w = pkrtz(h.z, h.w);
        }
        xh[swzrow(e)] = v;
    }
    __syncthreads();

    const int col = lane & 15, lg = lane >> 4;

    // ---- hoisted kt-invariant swizzled byte addresses (12) ----
    int addrs[12];
    #pragma unroll
    for (int i = 0; i < 4; ++i)
        #pragma unroll
        for (int kb = 0; kb < 3; ++kb) {
            const int e = 32 + col - 4 * dil + (w * 4 + i) * 16 + (kb * 4 + lg) * dil;
            addrs[i * 3 + kb] = swzrow(e) * 16;
        }

    for (int kt = 0; kt < 6; ++kt) {
        hf8 af[3];
        #pragma unroll
        for (int kb = 0; kb < 3; ++kb)
            af[kb] = __builtin_bit_cast(hf8, Alds[(kt * 3 + kb) * 64 + lane]);

        float4 bq[4];
        #pragma unroll
        for (int rg = 0; rg < 4; ++rg) {
            int k = kt * 16 + lg * 4 + rg;
            k = (k < TK) ? k : (TK - 1);
            bq[rg] = blds[k];
        }

        u32 c[16];
        #pragma unroll
        for (int z = 0; z < 16; ++z) c[z] = 0u;

        #pragma unroll
        for (int i = 0; i < 4; ++i) {
            f32x4 C = {0.f, 0.f, 0.f, 0.f};
            #pragma unroll
            for (int kb = 0; kb < 3; ++kb) {
                const hf8 bf = *(const hf8*)((const char*)xh + addrs[i * 3 + kb]);
                C = __builtin_amdgcn_mfma_f32_16x16x32_f16(af[kb], bf, C, 0, 0, 0);
            }
            const int tfirst = t0 + (w * 4 + i) * 16;   // wave-uniform
            if (tfirst >= pad && tfirst + 16 <= TL - pad) {
                // interior fast path: no trim anywhere (cmp+addc)
                #pragma unroll
                for (int rg = 0; rg < 4; ++rg) {
                    const float cv = C[rg];
                    c[rg * 4 + 0] += cv > bq[rg].x;
                    c[rg * 4 + 1] += cv > bq[rg].y;
                    c[rg * 4 + 2] += cv > bq[rg].z;
                    c[rg * 4 + 3] += cv > bq[rg].w;
                }
            } else {
                const int t = tfirst + col;
                const bool ok = (t >= pad && t < TL - pad);
                #pragma unroll
                for (int rg = 0; rg < 4; ++rg) {
                    const float cv = C[rg];
                    const bool use = ((d ^ rg) & 1) ? ok : true;  // trim iff (d+k) odd
                    c[rg * 4 + 0] += (use && cv > bq[rg].x) ? 1u : 0u;
                    c[rg * 4 + 1] += (use && cv > bq[rg].y) ? 1u : 0u;
                    c[rg * 4 + 2] += (use && cv > bq[rg].z) ? 1u : 0u;
                    c[rg * 4 + 3] += (use && cv > bq[rg].w) ? 1u : 0u;
                }
            }
        }

        // pack to bytes (each count <= 4; reduced over 16 lanes <= 64) and reduce
        u32 p[4];
        #pragma unroll
        for (int rg = 0; rg < 4; ++rg)
            p[rg] = c[rg * 4] | (c[rg * 4 + 1] << 8) | (c[rg * 4 + 2] << 16) | (c[rg * 4 + 3] << 24);
        #pragma unroll
        for (int m = 1; m < 16; m <<= 1)
            #pragma unroll
            for (int rg = 0; rg < 4; ++rg)
                p[rg] += __shfl_xor(p[rg], m, 64);

        if (col == 0) {
            #pragma unroll
            for (int rg = 0; rg < 4; ++rg) {
                const int k = kt * 16 + lg * 4 + rg;
                if (k < TK) {
                    #pragma unroll
                    for (int f = 0; f < 4; ++f)
                        atomicAdd(&feats[k][f], (int)((p[rg] >> (8 * f)) & 0xFFu));
                }
            }
        }
    }

    // ---- epilogue: plain coalesced partial stores ----
    __syncthreads();
    for (int idx = tid; idx < KF; idx += 256)
        ws[(size_t)bx * KF + idx] = feats[idx >> 2][idx & 3];
}

// Reduce 8 q-partials, normalize, write out. Grid covers 64*NFEAT exactly.
__global__ void mr_fin(const int* __restrict__ ws, const float* __restrict__ fmean,
                       const float* __restrict__ fstd, float* __restrict__ out) {
    const int o = blockIdx.x * 256 + threadIdx.x;
    const int fid = o % NFEAT, b = o / NFEAT;
    const int d = fid / KF, idx = fid % KF, k = idx >> 2;
    const int base = ((b * 32 + d * 8) * KF) + idx;
    int cnt = 0;
    #pragma unroll
    for (int q = 0; q < NQ; ++q) cnt += ws[base + q * KF];
    const float denom = ((d + k) & 1) ? (float)(TL - (8 << d)) : (float)TL;
    out[o] = ((float)cnt / denom - fmean[fid]) / fstd[fid];
}

extern "C" void kernel_launch(void* const* d_in, const int* in_sizes, int n_in,
                              void* d_out, int out_size, void* d_ws, size_t ws_size,
                              hipStream_t stream) {
    const float* x     = (const float*)d_in[0];
    const float* kern  = (const float*)d_in[1];
    const float* cmask = (const float*)d_in[2];
    const float* bias  = (const float*)d_in[3];
    const float* fmean = (const float*)d_in[4];
    const float* fstd  = (const float*)d_in[5];
    float* out = (float*)d_out;
    int* ws = (int*)d_ws;   // 2048*336*4 = 2752512 B

    hipLaunchKernelGGL(mr_main, dim3(64 * TD * NQ), dim3(256), 0, stream,
                       x, kern, cmask, bias, ws);
    hipLaunchKernelGGL(mr_fin, dim3(64 * NFEAT / 256), dim3(256), 0, stream,
                       ws, fmean, fstd, out);
}

// Round 18
// 35.401 us; speedup vs baseline: 6.9764x; 1.0910x over previous
//
#include <hip/hip_runtime.h>

#define TL 2048
#define TC 8
#define TK 84
#define TF 4
#define TD 4
#define ROWS 352            // staged LDS rows of 16B: 320 ext + swizzle pad
#define NFEAT (TD * TK * TF)  // 1344
#define KF (TK * TF)          // 336
#define NQ 8                  // t-chunks per (b,d)

typedef unsigned int u32;
typedef __fp16 hf8 __attribute__((ext_vector_type(8)));
typedef float f32x4 __attribute__((ext_vector_type(4)));

__device__ __forceinline__ u32 pkrtz(float a, float b) {
    return __builtin_bit_cast(u32, __builtin_amdgcn_cvt_pkrtz(a, b));
}
// row swizzle: breaks the 8-row bank period of 16B rows; involution per 8-row group
__device__ __forceinline__ int swzrow(int e) { return e ^ ((e >> 3) & 7); }

__global__ __launch_bounds__(256, 4) void mr_main(
    const float* __restrict__ x,     // [B, L, C]
    const float* __restrict__ kern,  // [K, 9]
    const float* __restrict__ cmask, // [D, K, C]
    const float* __restrict__ bias,  // [D, TK, TF]
    int* __restrict__ ws)            // [2048][KF] per-block partial counts
{
    __shared__ __align__(16) uint4 xh[ROWS];     // 5632 B fp16 signal, [t][c] rows
    __shared__ __align__(16) uint4 Alds[1152];   // 18432 B masked-weight fragments
    __shared__ __align__(16) float4 blds[TK];    // 1344 B biases
    __shared__ u32 feats2[6][4][16];             // [kt][wave][lg*4+rg] packed bytes, 1536 B

    const int bx = blockIdx.x;
    const int q = bx & 7, d = (bx >> 3) & 3, b = bx >> 5;
    const int tid = threadIdx.x, lane = tid & 63, w = tid >> 6;
    const int dil = 1 << d, pad = 4 << d;
    const int t0 = q * 256;
    const float* xb = x + (size_t)b * TL * TC;

    if (tid < TK) blds[tid] = *(const float4*)(bias + ((size_t)d * TK + tid) * TF);

    // ---- build A fragments in LDS: Alds[(kt*3+kb)*64 + lg*16 + col] ----
    for (int f = tid; f < 1152; f += 256) {
        const int col = f & 15, lg = (f >> 4) & 3, kbkt = f >> 6;
        const int kt = kbkt / 3, kb = kbkt % 3;
        const int k = kt * 16 + col, j = kb * 4 + lg;
        uint4 v = {0u, 0u, 0u, 0u};
        if (k < TK && j < 9) {
            const float wv = kern[k * 9 + j];
            const float* mp = cmask + ((size_t)d * TK + k) * TC;
            const float4 m0 = *(const float4*)mp;
            const float4 m1 = *(const float4*)(mp + 4);
            v.x = pkrtz(m0.x != 0.f ? wv : 0.f, m0.y != 0.f ? wv : 0.f);
            v.y = pkrtz(m0.z != 0.f ? wv : 0.f, m0.w != 0.f ? wv : 0.f);
            v.z = pkrtz(m1.x != 0.f ? wv : 0.f, m1.y != 0.f ? wv : 0.f);
            v.w = pkrtz(m1.z != 0.f ? wv : 0.f, m1.w != 0.f ? wv : 0.f);
        }
        Alds[f] = v;
    }

    // ---- stage x (fp16, row-swizzled); OOB rows zeroed ----
    for (int e = tid; e < ROWS; e += 256) {
        const int pos = t0 - 32 + e;
        uint4 v = {0u, 0u, 0u, 0u};
        if (pos >= 0 && pos < TL) {
            const float4* xp = (const float4*)(xb + (size_t)pos * TC);
            const float4 a = xp[0], h = xp[1];
            v.x = pkrtz(a.x, a.y); v.y = pkrtz(a.z, a.w);
            v.z = pkrtz(h.x, h.y); v.w = pkrtz(h.z, h.w);
        }
        xh[swzrow(e)] = v;
    }
    __syncthreads();

    const int col = lane & 15, lg = lane >> 4;

    // ---- hoist ALL kt-invariant B-fragments into registers (12 x hf8) ----
    hf8 bf[12];
    #pragma unroll
    for (int i = 0; i < 4; ++i)
        #pragma unroll
        for (int kb = 0; kb < 3; ++kb) {
            const int e = 32 + col - 4 * dil + (w * 4 + i) * 16 + (kb * 4 + lg) * dil;
            bf[i * 3 + kb] = __builtin_bit_cast(hf8, xh[swzrow(e)]);
        }

    // wave-uniform interior tests per i (t-tile fully inside [pad, TL-pad))
    bool interior[4];
    #pragma unroll
    for (int i = 0; i < 4; ++i) {
        const int tfirst = t0 + (w * 4 + i) * 16;
        interior[i] = (tfirst >= pad) && (tfirst + 16 <= TL - pad);
    }

    for (int kt = 0; kt < 6; ++kt) {
        hf8 af[3];
        #pragma unroll
        for (int kb = 0; kb < 3; ++kb)
            af[kb] = __builtin_bit_cast(hf8, Alds[(kt * 3 + kb) * 64 + lane]);

        float4 bq[4];
        #pragma unroll
        for (int rg = 0; rg < 4; ++rg) {
            int k = kt * 16 + lg * 4 + rg;
            k = (k < TK) ? k : (TK - 1);
            bq[rg] = blds[k];
        }

        // packed byte counters: field f at bits [8f,8f+8); per-lane <=4, reduced <=64
        u32 cnt[4] = {0u, 0u, 0u, 0u};

        #pragma unroll
        for (int i = 0; i < 4; ++i) {
            f32x4 C = {0.f, 0.f, 0.f, 0.f};
            #pragma unroll
            for (int kb = 0; kb < 3; ++kb)
                C = __builtin_amdgcn_mfma_f32_16x16x32_f16(af[kb], bf[i * 3 + kb], C, 0, 0, 0);

            if (interior[i]) {
                #pragma unroll
                for (int rg = 0; rg < 4; ++rg) {
                    const float cv = C[rg];
                    cnt[rg] += (cv > bq[rg].x) ? 0x1u : 0u;
                    cnt[rg] += (cv > bq[rg].y) ? 0x100u : 0u;
                    cnt[rg] += (cv > bq[rg].z) ? 0x10000u : 0u;
                    cnt[rg] += (cv > bq[rg].w) ? 0x1000000u : 0u;
                }
            } else {
                const int t = t0 + (w * 4 + i) * 16 + col;
                const bool ok = (t >= pad && t < TL - pad);
                #pragma unroll
                for (int rg = 0; rg < 4; ++rg) {
                    const float cv = C[rg];
                    const bool use = ((d ^ rg) & 1) ? ok : true;  // trim iff (d+k) odd
                    cnt[rg] += (use && cv > bq[rg].x) ? 0x1u : 0u;
                    cnt[rg] += (use && cv > bq[rg].y) ? 0x100u : 0u;
                    cnt[rg] += (use && cv > bq[rg].z) ? 0x10000u : 0u;
                    cnt[rg] += (use && cv > bq[rg].w) ? 0x1000000u : 0u;
                }
            }
        }

        // reduce over the 16 t-columns (lane bits 0..3); packed adds can't carry
        #pragma unroll
        for (int m = 1; m < 16; m <<= 1)
            #pragma unroll
            for (int rg = 0; rg < 4; ++rg)
                cnt[rg] += __shfl_xor(cnt[rg], m, 64);

        // one non-atomic store set per (kt, wave): lanes 0/16/32/48 write disjoint slots
        if (col == 0) {
            #pragma unroll
            for (int rg = 0; rg < 4; ++rg)
                feats2[kt][w][lg * 4 + rg] = cnt[rg];
        }
    }

    // ---- epilogue: unpack per-wave partials, sum over waves, plain stores ----
    __syncthreads();
    for (int idx = tid; idx < KF; idx += 256) {
        const int k = idx >> 2, f = idx & 3;
        const int kt = k >> 4, r = k & 15;      // r = lg*4+rg
        int cnt = 0;
        #pragma unroll
        for (int wv = 0; wv < 4; ++wv)
            cnt += (int)((feats2[kt][wv][r] >> (8 * f)) & 0xFFu);
        ws[(size_t)bx * KF + idx] = cnt;
    }
}

// Reduce 8 q-partials, normalize, write out. Grid covers 64*NFEAT exactly.
__global__ void mr_fin(const int* __restrict__ ws, const float* __restrict__ fmean,
                       const float* __restrict__ fstd, float* __restrict__ out) {
    const int o = blockIdx.x * 256 + threadIdx.x;
    const int fid = o % NFEAT, b = o / NFEAT;
    const int d = fid / KF, idx = fid % KF, k = idx >> 2;
    const int base = ((b * 32 + d * 8) * KF) + idx;
    int cnt = 0;
    #pragma unroll
    for (int q = 0; q < NQ; ++q) cnt += ws[base + q * KF];
    const float denom = ((d + k) & 1) ? (float)(TL - (8 << d)) : (float)TL;
    out[o] = ((float)cnt / denom - fmean[fid]) / fstd[fid];
}

extern "C" void kernel_launch(void* const* d_in, const int* in_sizes, int n_in,
                              void* d_out, int out_size, void* d_ws, size_t ws_size,
                              hipStream_t stream) {
    const float* x     = (const float*)d_in[0];
    const float* kern  = (const float*)d_in[1];
    const float* cmask = (const float*)d_in[2];
    const float* bias  = (const float*)d_in[3];
    const float* fmean = (const float*)d_in[4];
    const float* fstd  = (const float*)d_in[5];
    float* out = (float*)d_out;
    int* ws = (int*)d_ws;   // 2048*336*4 = 2752512 B

    hipLaunchKernelGGL(mr_main, dim3(64 * TD * NQ), dim3(256), 0, stream,
                       x, kern, cmask, bias, ws);
    hipLaunchKernelGGL(mr_fin, dim3(64 * NFEAT / 256), dim3(256), 0, stream,
                       ws, fmean, fstd, out);
}

// Round 19
// 33.840 us; speedup vs baseline: 7.2984x; 1.0462x over previous
//
#include <hip/hip_runtime.h>

#define TL 2048
#define TC 8
#define TK 84
#define TF 4
#define TD 4
#define ROWS 352            // staged LDS rows of 16B: 320 ext + swizzle pad
#define NFEAT (TD * TK * TF)  // 1344
#define KF (TK * TF)          // 336
#define NQ 8                  // t-chunks per (b,d)

typedef unsigned int u32;
typedef __fp16 hf8 __attribute__((ext_vector_type(8)));
typedef float f32x4 __attribute__((ext_vector_type(4)));

__device__ __forceinline__ u32 pkrtz(float a, float b) {
    return __builtin_bit_cast(u32, __builtin_amdgcn_cvt_pkrtz(a, b));
}
// row swizzle: breaks the 8-row bank period of 16B rows; involution per 8-row group
__device__ __forceinline__ int swzrow(int e) { return e ^ ((e >> 3) & 7); }

// sum over the 16 lanes of each col-group via DPP (VALU only, no LDS)
__device__ __forceinline__ u32 red16(u32 v) {
    v += (u32)__builtin_amdgcn_update_dpp(0, (int)v, 0xB1,  0xF, 0xF, true); // xor1
    v += (u32)__builtin_amdgcn_update_dpp(0, (int)v, 0x4E,  0xF, 0xF, true); // xor2
    v += (u32)__builtin_amdgcn_update_dpp(0, (int)v, 0x141, 0xF, 0xF, true); // xor7 == xor4 here
    v += (u32)__builtin_amdgcn_update_dpp(0, (int)v, 0x140, 0xF, 0xF, true); // xor15 == xor8 here
    return v;
}

__global__ __launch_bounds__(256, 4) void mr_main(
    const float* __restrict__ x,     // [B, L, C]
    const float* __restrict__ kern,  // [K, 9]
    const float* __restrict__ cmask, // [D, K, C]
    const float* __restrict__ bias,  // [D, TK, TF]
    int* __restrict__ ws)            // [2048][KF] per-block partial counts
{
    __shared__ __align__(16) uint4 xh[ROWS];     // 5632 B fp16 signal, [t][c] rows
    __shared__ __align__(16) uint4 Alds[1152];   // 18432 B masked-weight fragments
    __shared__ __align__(16) float4 blds[TK];    // 1344 B biases
    __shared__ u32 feats2[6][4][16];             // [kt][wave][lg*4+rg] packed bytes

    const int bx = blockIdx.x;
    const int q = bx & 7, d = (bx >> 3) & 3, b = bx >> 5;
    const int tid = threadIdx.x, lane = tid & 63, w = tid >> 6;
    const int dil = 1 << d, pad = 4 << d;
    const int t0 = q * 256;
    const float* xb = x + (size_t)b * TL * TC;

    if (tid < TK) blds[tid] = *(const float4*)(bias + ((size_t)d * TK + tid) * TF);

    // ---- build A fragments in LDS: Alds[(kt*3+kb)*64 + lg*16 + col] ----
    for (int f = tid; f < 1152; f += 256) {
        const int col = f & 15, lg = (f >> 4) & 3, kbkt = f >> 6;
        const int kt = kbkt / 3, kb = kbkt % 3;
        const int k = kt * 16 + col, j = kb * 4 + lg;
        uint4 v = {0u, 0u, 0u, 0u};
        if (k < TK && j < 9) {
            const float wv = kern[k * 9 + j];
            const float* mp = cmask + ((size_t)d * TK + k) * TC;
            const float4 m0 = *(const float4*)mp;
            const float4 m1 = *(const float4*)(mp + 4);
            v.x = pkrtz(m0.x != 0.f ? wv : 0.f, m0.y != 0.f ? wv : 0.f);
            v.y = pkrtz(m0.z != 0.f ? wv : 0.f, m0.w != 0.f ? wv : 0.f);
            v.z = pkrtz(m1.x != 0.f ? wv : 0.f, m1.y != 0.f ? wv : 0.f);
            v.w = pkrtz(m1.z != 0.f ? wv : 0.f, m1.w != 0.f ? wv : 0.f);
        }
        Alds[f] = v;
    }

    // ---- stage x (fp16, row-swizzled); OOB rows zeroed ----
    for (int e = tid; e < ROWS; e += 256) {
        const int pos = t0 - 32 + e;
        uint4 v = {0u, 0u, 0u, 0u};
        if (pos >= 0 && pos < TL) {
            const float4* xp = (const float4*)(xb + (size_t)pos * TC);
            const float4 a = xp[0], h = xp[1];
            v.x = pkrtz(a.x, a.y); v.y = pkrtz(a.z, a.w);
            v.z = pkrtz(h.x, h.y); v.w = pkrtz(h.z, h.w);
        }
        xh[swzrow(e)] = v;
    }
    __syncthreads();

    const int col = lane & 15, lg = lane >> 4;

    // ---- hoist ALL kt-invariant B-fragments into registers (12 x hf8) ----
    hf8 bf[12];
    #pragma unroll
    for (int i = 0; i < 4; ++i)
        #pragma unroll
        for (int kb = 0; kb < 3; ++kb) {
            const int e = 32 + col - 4 * dil + (w * 4 + i) * 16 + (kb * 4 + lg) * dil;
            bf[i * 3 + kb] = __builtin_bit_cast(hf8, xh[swzrow(e)]);
        }

    // wave-uniform interior tests per i (t-tile fully inside [pad, TL-pad))
    bool interior[4];
    #pragma unroll
    for (int i = 0; i < 4; ++i) {
        const int tfirst = t0 + (w * 4 + i) * 16;
        interior[i] = (tfirst >= pad) && (tfirst + 16 <= TL - pad);
    }

    for (int kt = 0; kt < 6; ++kt) {
        hf8 af[3];
        #pragma unroll
        for (int kb = 0; kb < 3; ++kb)
            af[kb] = __builtin_bit_cast(hf8, Alds[(kt * 3 + kb) * 64 + lane]);

        float4 bq[4];
        #pragma unroll
        for (int rg = 0; rg < 4; ++rg) {
            int k = kt * 16 + lg * 4 + rg;
            k = (k < TK) ? k : (TK - 1);
            bq[rg] = blds[k];
        }

        // packed byte counters: field f at bits [8f,8f+8); per-lane <=4, reduced <=64
        u32 cnt[4] = {0u, 0u, 0u, 0u};

        #pragma unroll
        for (int i = 0; i < 4; ++i) {
            f32x4 C = {0.f, 0.f, 0.f, 0.f};
            #pragma unroll
            for (int kb = 0; kb < 3; ++kb)
                C = __builtin_amdgcn_mfma_f32_16x16x32_f16(af[kb], bf[i * 3 + kb], C, 0, 0, 0);

            if (interior[i]) {
                #pragma unroll
                for (int rg = 0; rg < 4; ++rg) {
                    const float cv = C[rg];
                    cnt[rg] += (cv > bq[rg].x) ? 0x1u : 0u;
                    cnt[rg] += (cv > bq[rg].y) ? 0x100u : 0u;
                    cnt[rg] += (cv > bq[rg].z) ? 0x10000u : 0u;
                    cnt[rg] += (cv > bq[rg].w) ? 0x1000000u : 0u;
                }
            } else {
                const int t = t0 + (w * 4 + i) * 16 + col;
                const bool ok = (t >= pad && t < TL - pad);
                #pragma unroll
                for (int rg = 0; rg < 4; ++rg) {
                    const float cv = C[rg];
                    const bool use = ((d ^ rg) & 1) ? ok : true;  // trim iff (d+k) odd
                    cnt[rg] += (use && cv > bq[rg].x) ? 0x1u : 0u;
                    cnt[rg] += (use && cv > bq[rg].y) ? 0x100u : 0u;
                    cnt[rg] += (use && cv > bq[rg].z) ? 0x10000u : 0u;
                    cnt[rg] += (use && cv > bq[rg].w) ? 0x1000000u : 0u;
                }
            }
        }

        // reduce over the 16 t-columns via DPP (VALU); packed adds can't carry
        #pragma unroll
        for (int rg = 0; rg < 4; ++rg) cnt[rg] = red16(cnt[rg]);

        // one non-atomic store set per (kt, wave): lanes 0/16/32/48 write disjoint slots
        if (col == 0) {
            #pragma unroll
            for (int rg = 0; rg < 4; ++rg)
                feats2[kt][w][lg * 4 + rg] = cnt[rg];
        }
    }

    // ---- epilogue: unpack per-wave partials, sum over waves, plain stores ----
    __syncthreads();
    for (int idx = tid; idx < KF; idx += 256) {
        const int k = idx >> 2, f = idx & 3;
        const int kt = k >> 4, r = k & 15;      // r = lg*4+rg
        int cnt = 0;
        #pragma unroll
        for (int wv = 0; wv < 4; ++wv)
            cnt += (int)((feats2[kt][wv][r] >> (8 * f)) & 0xFFu);
        ws[(size_t)bx * KF + idx] = cnt;
    }
}

// Reduce 8 q-partials, normalize, write out. Grid covers 64*NFEAT exactly.
__global__ void mr_fin(const int* __restrict__ ws, const float* __restrict__ fmean,
                       const float* __restrict__ fstd, float* __restrict__ out) {
    const int o = blockIdx.x * 256 + threadIdx.x;
    const int fid = o % NFEAT, b = o / NFEAT;
    const int d = fid / KF, idx = fid % KF, k = idx >> 2;
    const int base = ((b * 32 + d * 8) * KF) + idx;
    int cnt = 0;
    #pragma unroll
    for (int q = 0; q < NQ; ++q) cnt += ws[base + q * KF];
    const float denom = ((d + k) & 1) ? (float)(TL - (8 << d)) : (float)TL;
    out[o] = ((float)cnt / denom - fmean[fid]) / fstd[fid];
}

extern "C" void kernel_launch(void* const* d_in, const int* in_sizes, int n_in,
                              void* d_out, int out_size, void* d_ws, size_t ws_size,
                              hipStream_t stream) {
    const float* x     = (const float*)d_in[0];
    const float* kern  = (const float*)d_in[1];
    const float* cmask = (const float*)d_in[2];
    const float* bias  = (const float*)d_in[3];
    const float* fmean = (const float*)d_in[4];
    const float* fstd  = (const float*)d_in[5];
    float* out = (float*)d_out;
    int* ws = (int*)d_ws;   // 2048*336*4 = 2752512 B

    hipLaunchKernelGGL(mr_main, dim3(64 * TD * NQ), dim3(256), 0, stream,
                       x, kern, cmask, bias, ws);
    hipLaunchKernelGGL(mr_fin, dim3(64 * NFEAT / 256), dim3(256), 0, stream,
                       ws, fmean, fstd, out);
}